// Round 2
// baseline (1641.098 us; speedup 1.0000x reference)
//
#include <hip/hip_runtime.h>
#include <math.h>

#define H 256
#define RPB 32
#define NRAYS 16384
#define MAX_ITERS_ 32
#define NEAR_ 0.8f
#define FAR_ 6.0f
#define EPS_ 1e-5f

__global__ __launch_bounds__(256, 2)
void sphere_trace(const float* __restrict__ origins,
                  const float* __restrict__ directions,
                  const float* __restrict__ W1, const float* __restrict__ b1,
                  const float* __restrict__ W2, const float* __restrict__ b2,
                  const float* __restrict__ W3, const float* __restrict__ b3,
                  const float* __restrict__ Wc1, const float* __restrict__ bc1,
                  const float* __restrict__ Wc2, const float* __restrict__ bc2,
                  float* __restrict__ out)
{
    __shared__ float h1s[RPB * H];           // 32 KiB activations [r][k]
    __shared__ float vT[H * (RPB + 1)];      // 33.8 KiB transposed partials [c][r], pad->2-way banks
    __shared__ float pxs[RPB], pys[RPB], pzs[RPB];
    __shared__ float wc2s[H * 3];

    const int tid = threadIdx.x;
    const int c = tid;                       // output column this thread owns
    const int r0 = blockIdx.x * RPB;

    // per-column weight preloads (held in registers across all iterations)
    const float w1x = W1[c], w1y = W1[H + c], w1z = W1[2*H + c];
    const float b1c = b1[c];
    const float b2c = b2[c];
    const float w3c = W3[c];
    const float wc1x = Wc1[c], wc1y = Wc1[H + c], wc1z = Wc1[2*H + c];
    const float bc1c = bc1[c];
    const float b3v = b3[0];

    wc2s[tid]       = Wc2[tid];
    wc2s[tid + 256] = Wc2[tid + 256];
    wc2s[tid + 512] = Wc2[tid + 512];

    // ray state lives in registers of threads 0..RPB-1
    float ox=0, oy=0, oz=0, dxx=0, dyy=0, dzz=0, sx=0, sy=0, sz=0, t=0.f;
    int active = 0;
    if (tid < RPB) {
        const int ray = r0 + tid;
        ox = origins[ray*3+0]; oy = origins[ray*3+1]; oz = origins[ray*3+2];
        dxx = directions[ray*3+0]; dyy = directions[ray*3+1]; dzz = directions[ray*3+2];
        sx = ox + dxx*NEAR_; sy = oy + dyy*NEAR_; sz = oz + dzz*NEAR_;
        active = 1;
        pxs[tid]=sx; pys[tid]=sy; pzs[tid]=sz;   // p0 = start
    }
    __syncthreads();

    for (int it = 0; it < MAX_ITERS_; ++it) {
        // ---- stage 1: h1[r][c] = relu(p_r . W1col_c + b1c)  (p reads are LDS broadcast)
        #pragma unroll 8
        for (int r = 0; r < RPB; ++r) {
            float hv = fmaf(pxs[r], w1x, fmaf(pys[r], w1y, fmaf(pzs[r], w1z, b1c)));
            h1s[r*H + c] = fmaxf(hv, 0.f);
        }
        __syncthreads();

        // ---- stage 2: h2[r][c] = relu(sum_k h1[r][k]*W2[k][c] + b2c); fold W3
        float acc[RPB];
        #pragma unroll
        for (int r = 0; r < RPB; ++r) acc[r] = b2c;

        const float* __restrict__ w2p = W2 + c;
        float wv0 = w2p[0], wv1 = w2p[H], wv2 = w2p[2*H], wv3 = w2p[3*H];
        for (int kq = 0; kq < H/4; ++kq) {
            const int kn = (kq + 1 < H/4) ? (kq + 1) : kq;   // software-pipelined weight loads
            const float wn0 = w2p[(4*kn+0)*H];
            const float wn1 = w2p[(4*kn+1)*H];
            const float wn2 = w2p[(4*kn+2)*H];
            const float wn3 = w2p[(4*kn+3)*H];
            #pragma unroll
            for (int rg = 0; rg < RPB; rg += 8) {
                float4 hq[8];
                #pragma unroll
                for (int rr = 0; rr < 8; ++rr)
                    hq[rr] = *reinterpret_cast<const float4*>(&h1s[(rg+rr)*H + 4*kq]);
                #pragma unroll
                for (int rr = 0; rr < 8; ++rr) {
                    float a = acc[rg+rr];
                    a = fmaf(hq[rr].x, wv0, a);
                    a = fmaf(hq[rr].y, wv1, a);
                    a = fmaf(hq[rr].z, wv2, a);
                    a = fmaf(hq[rr].w, wv3, a);
                    acc[rg+rr] = a;
                }
            }
            wv0=wn0; wv1=wn1; wv2=wn2; wv3=wn3;
        }
        #pragma unroll
        for (int r = 0; r < RPB; ++r)
            vT[c*(RPB+1) + r] = fmaxf(acc[r], 0.f) * w3c;
        __syncthreads();

        // ---- reduce + per-ray update (threads 0..RPB-1)
        int cond = 0;
        if (tid < RPB) {
            float s = b3v;
            #pragma unroll 4
            for (int cc = 0; cc < H; ++cc) s += vT[cc*(RPB+1) + tid];
            const float nx = pxs[tid], ny = pys[tid], nz = pzs[tid];
            const float nrm = sqrtf(nx*nx + ny*ny + nz*nz);
            cond = active && (s > EPS_) && (nrm < FAR_);
            if (cond) t += s;
            active = cond;
            pxs[tid] = sx + t*dxx;
            pys[tid] = sy + t*dyy;
            pzs[tid] = sz + t*dzz;
        }
        if (!__syncthreads_or(cond)) break;   // exact: inactive rays never change again
    }

    // ---- color network on final points (reuse vT as transposed h buffer)
    #pragma unroll 8
    for (int r = 0; r < RPB; ++r) {
        float hv = fmaf(pxs[r], wc1x, fmaf(pys[r], wc1y, fmaf(pzs[r], wc1z, bc1c)));
        vT[c*(RPB+1) + r] = fmaxf(hv, 0.f);
    }
    __syncthreads();

    if (tid < RPB) {
        float cr = bc2[0], cg = bc2[1], cb = bc2[2];
        for (int cc = 0; cc < H; ++cc) {
            const float h = vT[cc*(RPB+1) + tid];
            cr = fmaf(h, wc2s[cc*3+0], cr);
            cg = fmaf(h, wc2s[cc*3+1], cg);
            cb = fmaf(h, wc2s[cc*3+2], cb);
        }
        cr = 1.f/(1.f + expf(-cr));
        cg = 1.f/(1.f + expf(-cg));
        cb = 1.f/(1.f + expf(-cb));
        // mask: points != end (componentwise); exact equality is measure-zero
        const float ex = ox + dxx*FAR_, ey = oy + dyy*FAR_, ez = oz + dzz*FAR_;
        const float fx = pxs[tid], fy = pys[tid], fz = pzs[tid];
        const bool mask = (fx != ex) || (fy != ey) || (fz != ez);
        const int ray = r0 + tid;
        out[ray*3+0] = mask ? cr : 0.f;
        out[ray*3+1] = mask ? cg : 0.f;
        out[ray*3+2] = mask ? cb : 0.f;
    }
}

extern "C" void kernel_launch(void* const* d_in, const int* in_sizes, int n_in,
                              void* d_out, int out_size, void* d_ws, size_t ws_size,
                              hipStream_t stream)
{
    const float* origins    = (const float*)d_in[0];
    const float* directions = (const float*)d_in[1];
    const float* W1  = (const float*)d_in[2];
    const float* b1  = (const float*)d_in[3];
    const float* W2  = (const float*)d_in[4];
    const float* b2  = (const float*)d_in[5];
    const float* W3  = (const float*)d_in[6];
    const float* b3  = (const float*)d_in[7];
    const float* Wc1 = (const float*)d_in[8];
    const float* bc1 = (const float*)d_in[9];
    const float* Wc2 = (const float*)d_in[10];
    const float* bc2 = (const float*)d_in[11];
    float* out = (float*)d_out;

    dim3 grid(NRAYS / RPB), block(256);
    sphere_trace<<<grid, block, 0, stream>>>(origins, directions, W1, b1, W2, b2,
                                             W3, b3, Wc1, bc1, Wc2, bc2, out);
}

// Round 10
// 883.557 us; speedup vs baseline: 1.8574x; 1.8574x over previous
//
#include <hip/hip_runtime.h>
#include <math.h>

#define H 256
#define RPB 32
#define NRAYS 16384
#define MAX_ITERS_ 32
#define NEAR_ 0.8f
#define FAR_ 6.0f
#define EPS_ 1e-5f
#define VTS 260   // vT row stride in floats; 260*4B=1040B rows: 16B-aligned, 4-bank-offset lanes

__device__ __forceinline__ void fma4(float4& a, float s, const float4& w) {
    a.x = fmaf(s, w.x, a.x);
    a.y = fmaf(s, w.y, a.y);
    a.z = fmaf(s, w.z, a.z);
    a.w = fmaf(s, w.w, a.w);
}

__global__ __launch_bounds__(256, 2)
void sphere_trace(const float* __restrict__ origins,
                  const float* __restrict__ directions,
                  const float* __restrict__ W1, const float* __restrict__ b1,
                  const float* __restrict__ W2, const float* __restrict__ b2,
                  const float* __restrict__ W3, const float* __restrict__ b3,
                  const float* __restrict__ Wc1, const float* __restrict__ bc1,
                  const float* __restrict__ Wc2, const float* __restrict__ bc2,
                  float* __restrict__ out)
{
    __shared__ float h1s[RPB * H];        // 32 KiB activations [r][k]
    __shared__ float vT[RPB * VTS];       // 33.3 KiB h2*w3 partials [r][c]
    __shared__ float pxs[RPB], pys[RPB], pzs[RPB];
    __shared__ float wc2s[H * 3];

    const int tid = threadIdx.x;
    const int c = tid;                    // stage-1 / color-stage column
    const int rg = tid >> 6;              // stage-2 row-group: rows 8*rg .. 8*rg+7
    const int cg = tid & 63;              // stage-2 col-group: cols 4*cg .. 4*cg+3
    const int c0 = cg * 4;
    const int r0 = blockIdx.x * RPB;

    // per-column weight preloads (registers, live across all iterations)
    const float w1x = W1[c], w1y = W1[H + c], w1z = W1[2*H + c];
    const float b1c = b1[c];
    const float wc1x = Wc1[c], wc1y = Wc1[H + c], wc1z = Wc1[2*H + c];
    const float bc1c = bc1[c];
    const float b3v = b3[0];
    const float4 b2q = *reinterpret_cast<const float4*>(b2 + c0);
    const float4 w3q = *reinterpret_cast<const float4*>(W3 + c0);

    wc2s[tid]       = Wc2[tid];
    wc2s[tid + 256] = Wc2[tid + 256];
    wc2s[tid + 512] = Wc2[tid + 512];

    // ray state lives in registers of threads 0..RPB-1
    float ox=0, oy=0, oz=0, dxx=0, dyy=0, dzz=0, sx=0, sy=0, sz=0, t=0.f;
    int active = 0;
    if (tid < RPB) {
        const int ray = r0 + tid;
        ox = origins[ray*3+0]; oy = origins[ray*3+1]; oz = origins[ray*3+2];
        dxx = directions[ray*3+0]; dyy = directions[ray*3+1]; dzz = directions[ray*3+2];
        sx = ox + dxx*NEAR_; sy = oy + dyy*NEAR_; sz = oz + dzz*NEAR_;
        active = 1;
        pxs[tid]=sx; pys[tid]=sy; pzs[tid]=sz;   // p0 = start
    }
    __syncthreads();

    const float* __restrict__ w2p = W2 + c0;          // lane's 4-col slice base
    const float* __restrict__ hbase = h1s + (rg * 8) * H;

    for (int it = 0; it < MAX_ITERS_; ++it) {
        // ---- stage 1: h1[r][c] = relu(p_r . W1col_c + b1c)
        #pragma unroll 8
        for (int r = 0; r < RPB; ++r) {
            float hv = fmaf(pxs[r], w1x, fmaf(pys[r], w1y, fmaf(pzs[r], w1z, b1c)));
            h1s[r*H + c] = fmaxf(hv, 0.f);
        }
        __syncthreads();

        // ---- stage 2: thread computes h2 block [8 rows][4 cols], all 256 k
        float4 acc[8];
        #pragma unroll
        for (int rr = 0; rr < 8; ++rr) acc[rr] = b2q;

        float4 wA[4], hA[8], wB[4], hB[8];
        #pragma unroll
        for (int kk = 0; kk < 4; ++kk)
            wA[kk] = *reinterpret_cast<const float4*>(w2p + kk*H);
        #pragma unroll
        for (int rr = 0; rr < 8; ++rr)
            hA[rr] = *reinterpret_cast<const float4*>(hbase + rr*H);

        for (int kq = 0; kq < H/4; kq += 2) {
            {   // prefetch quad kq+1 -> B
                const int kn = kq + 1;
                #pragma unroll
                for (int kk = 0; kk < 4; ++kk)
                    wB[kk] = *reinterpret_cast<const float4*>(w2p + (kn*4 + kk)*H);
                #pragma unroll
                for (int rr = 0; rr < 8; ++rr)
                    hB[rr] = *reinterpret_cast<const float4*>(hbase + rr*H + 4*kn);
            }
            #pragma unroll
            for (int rr = 0; rr < 8; ++rr) {        // compute quad kq from A
                float4 a = acc[rr];
                fma4(a, hA[rr].x, wA[0]);
                fma4(a, hA[rr].y, wA[1]);
                fma4(a, hA[rr].z, wA[2]);
                fma4(a, hA[rr].w, wA[3]);
                acc[rr] = a;
            }
            {   // prefetch quad kq+2 -> A (clamped; tail loads unused)
                const int kn = (kq + 2 < H/4) ? (kq + 2) : (H/4 - 1);
                #pragma unroll
                for (int kk = 0; kk < 4; ++kk)
                    wA[kk] = *reinterpret_cast<const float4*>(w2p + (kn*4 + kk)*H);
                #pragma unroll
                for (int rr = 0; rr < 8; ++rr)
                    hA[rr] = *reinterpret_cast<const float4*>(hbase + rr*H + 4*kn);
            }
            #pragma unroll
            for (int rr = 0; rr < 8; ++rr) {        // compute quad kq+1 from B
                float4 a = acc[rr];
                fma4(a, hB[rr].x, wB[0]);
                fma4(a, hB[rr].y, wB[1]);
                fma4(a, hB[rr].z, wB[2]);
                fma4(a, hB[rr].w, wB[3]);
                acc[rr] = a;
            }
        }

        // relu, fold W3, write [8 rows][4 cols] as float4 rows into vT[r][c]
        #pragma unroll
        for (int rr = 0; rr < 8; ++rr) {
            float4 a = acc[rr];
            a.x = fmaxf(a.x, 0.f) * w3q.x;
            a.y = fmaxf(a.y, 0.f) * w3q.y;
            a.z = fmaxf(a.z, 0.f) * w3q.z;
            a.w = fmaxf(a.w, 0.f) * w3q.w;
            *reinterpret_cast<float4*>(&vT[(rg*8 + rr)*VTS + c0]) = a;
        }
        __syncthreads();

        // ---- reduce + per-ray update (threads 0..RPB-1); serial chain == round-0 order
        int cond = 0;
        if (tid < RPB) {
            float s = b3v;
            for (int j = 0; j < H/4; ++j) {
                const float4 v = *reinterpret_cast<const float4*>(&vT[tid*VTS + 4*j]);
                s += v.x; s += v.y; s += v.z; s += v.w;
            }
            const float nx = pxs[tid], ny = pys[tid], nz = pzs[tid];
            const float nrm = sqrtf(nx*nx + ny*ny + nz*nz);
            cond = active && (s > EPS_) && (nrm < FAR_);
            if (cond) t += s;
            active = cond;
            pxs[tid] = sx + t*dxx;
            pys[tid] = sy + t*dyy;
            pzs[tid] = sz + t*dzz;
        }
        if (!__syncthreads_or(cond)) break;   // exact: inactive rays never change again
    }

    // ---- color network on final points (vT reused row-major: [r][c])
    #pragma unroll 8
    for (int r = 0; r < RPB; ++r) {
        float hv = fmaf(pxs[r], wc1x, fmaf(pys[r], wc1y, fmaf(pzs[r], wc1z, bc1c)));
        vT[r*VTS + c] = fmaxf(hv, 0.f);
    }
    __syncthreads();

    if (tid < RPB) {
        float cr = bc2[0], cg2 = bc2[1], cb = bc2[2];
        for (int cc = 0; cc < H; ++cc) {
            const float h = vT[tid*VTS + cc];
            cr  = fmaf(h, wc2s[cc*3+0], cr);
            cg2 = fmaf(h, wc2s[cc*3+1], cg2);
            cb  = fmaf(h, wc2s[cc*3+2], cb);
        }
        cr  = 1.f/(1.f + expf(-cr));
        cg2 = 1.f/(1.f + expf(-cg2));
        cb  = 1.f/(1.f + expf(-cb));
        // mask: points != end (componentwise); exact equality is measure-zero
        const float ex = ox + dxx*FAR_, ey = oy + dyy*FAR_, ez = oz + dzz*FAR_;
        const float fx = pxs[tid], fy = pys[tid], fz = pzs[tid];
        const bool mask = (fx != ex) || (fy != ey) || (fz != ez);
        const int ray = r0 + tid;
        out[ray*3+0] = mask ? cr  : 0.f;
        out[ray*3+1] = mask ? cg2 : 0.f;
        out[ray*3+2] = mask ? cb  : 0.f;
    }
}

extern "C" void kernel_launch(void* const* d_in, const int* in_sizes, int n_in,
                              void* d_out, int out_size, void* d_ws, size_t ws_size,
                              hipStream_t stream)
{
    const float* origins    = (const float*)d_in[0];
    const float* directions = (const float*)d_in[1];
    const float* W1  = (const float*)d_in[2];
    const float* b1  = (const float*)d_in[3];
    const float* W2  = (const float*)d_in[4];
    const float* b2  = (const float*)d_in[5];
    const float* W3  = (const float*)d_in[6];
    const float* b3  = (const float*)d_in[7];
    const float* Wc1 = (const float*)d_in[8];
    const float* bc1 = (const float*)d_in[9];
    const float* Wc2 = (const float*)d_in[10];
    const float* bc2 = (const float*)d_in[11];
    float* out = (float*)d_out;

    dim3 grid(NRAYS / RPB), block(256);
    sphere_trace<<<grid, block, 0, stream>>>(origins, directions, W1, b1, W2, b2,
                                             W3, b3, Wc1, bc1, Wc2, bc2, out);
}